// Round 7
// baseline (888.398 us; speedup 1.0000x reference)
//
#include <hip/hip_runtime.h>
#include <stdint.h>

typedef unsigned short u16;
typedef __bf16 bf16x8 __attribute__((ext_vector_type(8)));
typedef float f32x4 __attribute__((ext_vector_type(4)));

__device__ __forceinline__ u16 f2b(float x) {
  uint32_t b = __float_as_uint(x);
  b += 0x7fff + ((b >> 16) & 1);
  return (u16)(b >> 16);
}
__device__ __forceinline__ float b2f(u16 u) {
  return __uint_as_float(((uint32_t)u) << 16);
}

#define GLD16(src, dst)                                                                  \
  __builtin_amdgcn_global_load_lds((const __attribute__((address_space(1))) void*)(src),\
                                   (__attribute__((address_space(3))) void*)(dst), 16, 0, 0)

__device__ __forceinline__ f32x4 mfma16(bf16x8 a, bf16x8 b, f32x4 c) {
  return __builtin_amdgcn_mfma_f32_16x16x32_bf16(a, b, c, 0, 0, 0);
}

// ---------------- RoPE cos/sin table
__global__ void k_rope_table(float2* __restrict__ tab) {
  int i = blockIdx.x * 256 + threadIdx.x;  // 65536 = 1024 * 64
  int l = i >> 6, d = i & 63;
  float inv = powf(10000.0f, -(float)(2 * d) / 128.0f);
  float ang = (float)l * inv;
  float s, c;
  sincosf(ang, &s, &c);
  tab[i] = make_float2(c, s);
}

// ---------------- fp32 -> bf16 cast, 8 elems/thread
__global__ void k_cast8(const float* __restrict__ src, u16* __restrict__ dst) {
  size_t i = (size_t)blockIdx.x * 256 + threadIdx.x;
  const float4* s4 = (const float4*)src;
  float4 a = s4[2 * i], b = s4[2 * i + 1];
  union { u16 u[8]; uint4 v; } o;
  o.u[0] = f2b(a.x); o.u[1] = f2b(a.y); o.u[2] = f2b(a.z); o.u[3] = f2b(a.w);
  o.u[4] = f2b(b.x); o.u[5] = f2b(b.y); o.u[6] = f2b(b.z); o.u[7] = f2b(b.w);
  ((uint4*)dst)[i] = o.v;
}

// ---------------- transpose-cast: src fp32 [R][C] -> dst bf16 [C][R]
__global__ __launch_bounds__(256) void k_tcast(const float* __restrict__ src,
                                               u16* __restrict__ dst, int R, int C) {
  __shared__ u16 t[64][72];
  int tiles_c = C >> 6;
  int tr = blockIdx.x / tiles_c, tc = blockIdx.x % tiles_c;
  int tid = threadIdx.x;
  {
    int rr = tid >> 4, cv = tid & 15;
#pragma unroll
    for (int it = 0; it < 4; ++it) {
      int row = rr + it * 16;
      float4 v = *(const float4*)(src + (size_t)(tr * 64 + row) * C + tc * 64 + cv * 4);
      t[row][cv * 4 + 0] = f2b(v.x);
      t[row][cv * 4 + 1] = f2b(v.y);
      t[row][cv * 4 + 2] = f2b(v.z);
      t[row][cv * 4 + 3] = f2b(v.w);
    }
  }
  __syncthreads();
  {
    int cc = tid >> 3, g = tid & 7;
#pragma unroll
    for (int it = 0; it < 2; ++it) {
      int c = cc + it * 32;
      union { u16 u[8]; uint4 v; } o;
#pragma unroll
      for (int j = 0; j < 8; ++j) o.u[j] = t[g * 8 + j][c];
      *(uint4*)(dst + (size_t)(tc * 64 + c) * R + tr * 64 + g * 8) = o.v;
    }
  }
}

// ---------------- V transpose
__global__ __launch_bounds__(256) void k_vtrans(const u16* __restrict__ qkv,
                                                u16* __restrict__ vrt) {
  __shared__ u16 t[64][72];
  int b = blockIdx.x >> 8;
  int tt = blockIdx.x & 255;
  int tr = tt >> 4, tc = tt & 15;
  int tid = threadIdx.x;
  {
    int rr = tid >> 3, g = tid & 7;
#pragma unroll
    for (int it = 0; it < 2; ++it) {
      int row = rr + it * 32;
      union { u16 u[8]; uint4 v; } o;
      o.v = *(const uint4*)(qkv + (size_t)(b * 1024 + tr * 64 + row) * 6144 + 5120 + tc * 64 + g * 8);
#pragma unroll
      for (int j = 0; j < 8; ++j) t[row][g * 8 + j] = o.u[j];
    }
  }
  __syncthreads();
  {
    int cc = tid >> 3, g = tid & 7;
#pragma unroll
    for (int it = 0; it < 2; ++it) {
      int c = cc + it * 32;
      union { u16 u[8]; uint4 v; } o;
#pragma unroll
      for (int j = 0; j < 8; ++j) o.u[j] = t[g * 8 + j][c];
      *(uint4*)(vrt + (size_t)(b * 1024 + tc * 64 + c) * 1024 + tr * 64 + g * 8) = o.v;
    }
  }
}

// ---------------- RoPE scatter
__global__ void k_rope(const u16* __restrict__ qkv, const float2* __restrict__ tab,
                       u16* __restrict__ qr, u16* __restrict__ kr) {
  int u = blockIdx.x * 256 + threadIdx.x;  // 4096 * 2560
  int row = u / 2560;
  int j = u - row * 2560;
  int b = row >> 10, l = row & 1023;
  const float scale = 0.08838834764831845f;  // 128^-0.5
  if (j < 2048) {
    int h = j >> 6, dp = j & 63;
    uint32_t pair = *(const uint32_t*)(qkv + (size_t)row * 6144 + h * 128 + 2 * dp);
    float2 cs = tab[l * 64 + dp];
    float x1 = b2f((u16)pair), x2 = b2f((u16)(pair >> 16));
    float r1 = (x1 * cs.x - x2 * cs.y) * scale;
    float r2 = (x1 * cs.y + x2 * cs.x) * scale;
    uint32_t outw = (uint32_t)f2b(r1) | ((uint32_t)f2b(r2) << 16);
    *(uint32_t*)(qr + ((size_t)((b * 32 + h) * 1024 + l)) * 128 + 2 * dp) = outw;
  } else {
    int jj = j - 2048;
    int kh = jj >> 6, dp = jj & 63;
    uint32_t pair = *(const uint32_t*)(qkv + (size_t)row * 6144 + 4096 + kh * 128 + 2 * dp);
    float2 cs = tab[l * 64 + dp];
    float x1 = b2f((u16)pair), x2 = b2f((u16)(pair >> 16));
    float r1 = x1 * cs.x - x2 * cs.y;
    float r2 = x1 * cs.y + x2 * cs.x;
    uint32_t outw = (uint32_t)f2b(r1) | ((uint32_t)f2b(r2) << 16);
    *(uint32_t*)(kr + ((size_t)((b * 8 + kh) * 1024 + l)) * 128 + 2 * dp) = outw;
  }
}

// ================= 256x256 8-phase bf16 GEMM, read-ahead-1 pipeline =================
// Schedule identical to R5/R6 (race-ledger verified, correctness-passed).
// R6->R7: pin the register budget with amdgpu_waves_per_eu(2,2).
// Evidence: launch_bounds(512,2) and (512,1) BOTH produced VGPR_Count=128 with
// 117MB of scratch spill -- the 2nd launch_bounds arg is only a MINIMUM; the
// backend's allocator still targets its default 4 waves/EU (512-reg pool / 4 =
// 128) and spills to get there. waves_per_eu(2,2) clamps the TARGET to 2
// waves/EU (= the actual residency: 128KiB LDS -> 1 block/CU -> 8 waves -> 2/EU),
// raising the cap to 256 regs; the pipeline needs ~210.
// Cycle model: per CU per phase LDS ~256cyc, MFMA ~155cyc. Serialized (R4) =
// 411cyc -> 38% util (matched). Overlapped (this) -> ~62% (m201's ceiling).

#define STAGE2(s0, s1, koff, ldsoff)          \
  GLD16((s0) + (koff), dst0 + (ldsoff));      \
  GLD16((s1) + (koff), dst1 + (ldsoff));

#define LOADB(dst, base, kh)                                              \
  dst[0] = *(const bf16x8*)((base) + (kh) * 8192 + 0 * 512);              \
  dst[1] = *(const bf16x8*)((base) + (kh) * 8192 + 1 * 512);              \
  dst[2] = *(const bf16x8*)((base) + (kh) * 8192 + 2 * 512);              \
  dst[3] = *(const bf16x8*)((base) + (kh) * 8192 + 3 * 512);

#define LOADA(dst, base, kh, mh)                                          \
  dst[0] = *(const bf16x8*)((base) + (kh) * 8192 + (mh) * 2048 + 0 * 512);\
  dst[1] = *(const bf16x8*)((base) + (kh) * 8192 + (mh) * 2048 + 1 * 512);\
  dst[2] = *(const bf16x8*)((base) + (kh) * 8192 + (mh) * 2048 + 2 * 512);\
  dst[3] = *(const bf16x8*)((base) + (kh) * 8192 + (mh) * 2048 + 3 * 512);

#define MFMA_PHASE(mh, AF, BF)                                            \
  asm volatile("s_waitcnt lgkmcnt(0)" ::: "memory");                      \
  __builtin_amdgcn_sched_barrier(0);                                      \
  __builtin_amdgcn_s_setprio(1);                                          \
  _Pragma("unroll") for (int mm = 0; mm < 4; ++mm)                        \
    _Pragma("unroll") for (int n_ = 0; n_ < 4; ++n_)                      \
      acc[(mh) * 4 + mm][n_] = mfma16(AF[mm], BF[n_], acc[(mh) * 4 + mm][n_]); \
  __builtin_amdgcn_s_setprio(0);                                          \
  __builtin_amdgcn_sched_barrier(0);

#define ENDP __builtin_amdgcn_s_barrier();

template <typename OutT>
__global__ __launch_bounds__(512)
__attribute__((amdgpu_waves_per_eu(2, 2)))
void k_gemm8(const u16* __restrict__ A,
             const u16* __restrict__ Bt,
             OutT* __restrict__ C,
             int M, int N, int K) {
  extern __shared__ u16 lds[];
  const int tid = threadIdx.x;
  const int lane = tid & 63, wid = tid >> 6;
  const int l16 = lane & 15, lhi = lane >> 4;
  const int wm = wid >> 2, wn = wid & 3;

  const int nbn = N >> 8;
  int bid = blockIdx.x;
  const int cpx = gridDim.x >> 3;
  bid = (bid & 7) * cpx + (bid >> 3);  // XCD swizzle (grid % 8 == 0)
  const int bm = (bid / nbn) << 8;
  const int bn = (bid % nbn) << 8;

  const u16* Ag = A + (size_t)bm * K;
  const u16* Bg = Bt + (size_t)bn * K;

  // ---- per-thread constant addresses ----
  const int swz = (lhi ^ ((l16 >> 1) & 3)) << 3;     // lane-constant swizzle
  const u16* pA0 = lds + wm * 4096 + l16 * 32 + swz;          // A reads, buf0
  const u16* pA1 = pA0 + 32768;                               // A reads, buf1
  const u16* pB0 = lds + 16384 + wn * 2048 + l16 * 32 + swz;  // B reads, buf0
  const u16* pB1 = pB0 + 32768;                               // B reads, buf1

  const int r0 = tid >> 2, g0 = tid & 3;     // stage chunk 0: rows 0..127
  const int r1 = r0 + 128;                   // stage chunk 1: rows 128..255
  const size_t so0 = (size_t)r0 * K + ((g0 ^ ((r0 >> 1) & 3)) << 3);
  const size_t so1 = (size_t)r1 * K + ((g0 ^ ((r1 >> 1) & 3)) << 3);
  const u16* sA0 = Ag + so0;
  const u16* sA1 = Ag + so1;
  const u16* sB0 = Bg + so0;
  const u16* sB1 = Bg + so1;
  u16* dst0 = lds + wid * 512;               // chunk0 LDS dest (wave-uniform base)
  u16* dst1 = lds + 4096 + wid * 512;        // chunk1 LDS dest

  f32x4 acc[8][4] = {};
  bf16x8 afrA[4], afrB[4], bfrA[4], bfrB[4];

  // ---- prologue: tile0 (buf0) fully; tile1 (buf1) B-k0, A-k0, B-k1
  STAGE2(sA0, sA1, 0, 0);            // A t0 kh0
  STAGE2(sA0, sA1, 32, 8192);        // A t0 kh1
  STAGE2(sB0, sB1, 0, 16384);        // B t0 kh0
  STAGE2(sB0, sB1, 32, 24576);       // B t0 kh1
  STAGE2(sB0, sB1, 64, 49152);       // B t1 kh0
  STAGE2(sA0, sA1, 64, 32768);       // A t1 kh0
  STAGE2(sB0, sB1, 96, 57344);       // B t1 kh1
  asm volatile("s_waitcnt vmcnt(6)" ::: "memory");
  __builtin_amdgcn_s_barrier();
  // pre-load P1 fragments (tile0, kh0, mh0)
  LOADB(bfrA, pB0, 0)
  LOADA(afrA, pA0, 0, 0)

  const int nt = K >> 6;
  for (int t = 0; t < nt; t += 2) {
    const bool more = (t + 2) < nt;
    const int kA1 = (t + 1) * 64 + 32;
    const int k2 = (t + 2) * 64;
    const int k3 = (t + 3) * 64;
    // P1: MFMA t kh0 mh0 | W1: read P2 frags; stage A-k1(t+1)->buf1
    MFMA_PHASE(0, afrA, bfrA)
    LOADA(afrB, pA0, 0, 1)
    STAGE2(sA0, sA1, kA1, 40960);
    ENDP
    // P2: MFMA t kh0 mh1 | W2: read P3 frags; stage B-k0(t+2)->buf0
    MFMA_PHASE(1, afrB, bfrA)
    LOADB(bfrB, pB0, 1)
    LOADA(afrA, pA0, 1, 0)
    if (more) { STAGE2(sB0, sB1, k2, 16384); }
    ENDP
    // P3: MFMA t kh1 mh0 | W3: read P4 frags; stage A-k0(t+2)->buf0
    MFMA_PHASE(0, afrA, bfrB)
    LOADA(afrB, pA0, 1, 1)
    if (more) { STAGE2(sA0, sA1, k2, 0); }
    ENDP
    // P4: MFMA t kh1 mh1 | W4: stage B-k1(t+2); vmcnt; read P5 frags (tile t+1)
    MFMA_PHASE(1, afrB, bfrB)
    if (more) {
      STAGE2(sB0, sB1, k2 + 32, 24576);
      asm volatile("s_waitcnt vmcnt(6)" ::: "memory");
    } else {
      asm volatile("s_waitcnt vmcnt(0)" ::: "memory");
    }
    LOADB(bfrA, pB1, 0)
    LOADA(afrA, pA1, 0, 0)
    ENDP
    // P5: MFMA t+1 kh0 mh0 | W5: read P6 frags; stage A-k1(t+2)->buf0
    MFMA_PHASE(0, afrA, bfrA)
    LOADA(afrB, pA1, 0, 1)
    if (more) { STAGE2(sA0, sA1, k2 + 32, 8192); }
    ENDP
    // P6: MFMA t+1 kh0 mh1 | W6: read P7 frags; stage B-k0(t+3)->buf1
    MFMA_PHASE(1, afrB, bfrA)
    LOADB(bfrB, pB1, 1)
    LOADA(afrA, pA1, 1, 0)
    if (more) { STAGE2(sB0, sB1, k3, 49152); }
    ENDP
    // P7: MFMA t+1 kh1 mh0 | W7: read P8 frags; stage A-k0(t+3)->buf1
    MFMA_PHASE(0, afrA, bfrB)
    LOADA(afrB, pA1, 1, 1)
    if (more) { STAGE2(sA0, sA1, k3, 32768); }
    ENDP
    // P8: MFMA t+1 kh1 mh1 | W8: stage B-k1(t+3); vmcnt; read next-P1 frags
    MFMA_PHASE(1, afrB, bfrB)
    if (more) {
      STAGE2(sB0, sB1, k3 + 32, 57344);
      asm volatile("s_waitcnt vmcnt(6)" ::: "memory");
      LOADB(bfrA, pB0, 0)
      LOADA(afrA, pA0, 0, 0)
    }
    ENDP
  }

  // ---- epilogue: C write
#pragma unroll
  for (int m = 0; m < 8; ++m) {
    int row = bm + wm * 128 + m * 16 + lhi * 4;
#pragma unroll
    for (int n = 0; n < 4; ++n) {
      int col = bn + wn * 64 + n * 16 + l16;
#pragma unroll
      for (int r = 0; r < 4; ++r) {
        float v = acc[m][n][r];
        size_t idx = (size_t)(row + r) * N + col;
        if constexpr (sizeof(OutT) == 2) C[idx] = f2b(v);
        else C[idx] = v;
      }
    }
  }
}

// ---------------- flash attention (unchanged)
__global__ __launch_bounds__(512) void k_attn(const u16* __restrict__ qr,
                                              const u16* __restrict__ kr,
                                              const u16* __restrict__ vrt,
                                              u16* __restrict__ ao) {
  __shared__ u16 Klds[8192];
  __shared__ u16 Vlds[8192];
  __shared__ u16 Plds[9216];
  int bid = blockIdx.x;
  int qb = bid & 7, h = (bid >> 3) & 31, b = bid >> 8;
  int kvh = h & 7;
  int lane = threadIdx.x & 63, w = threadIdx.x >> 6;
  int l16 = lane & 15, lhi = lane >> 4;
  int qmin = qb * 128 + w * 16;

  const u16* qbase = qr + ((size_t)((b * 32 + h) * 1024) + qmin + l16) * 128;
  bf16x8 aq[4];
#pragma unroll
  for (int kc = 0; kc < 4; ++kc) aq[kc] = *(const bf16x8*)(qbase + kc * 32 + lhi * 8);

  const u16* Kg = kr + (size_t)(b * 8 + kvh) * (1024 * 128);
  const u16* Vg = vrt + (size_t)(b * 8 + kvh) * (128 * 1024);

  float m_run[4] = {-1e30f, -1e30f, -1e30f, -1e30f};
  float l_run[4] = {0.f, 0.f, 0.f, 0.f};
  f32x4 o[8] = {};

  int nkb = 2 * qb + 2;
  for (int kb = 0; kb < nkb; ++kb) {
    int kv0 = kb * 64;
#pragma unroll
    for (int i = 0; i < 2; ++i) {
      int c = w * 128 + i * 64 + lane;
      int krow = c >> 4, g = c & 15;
      GLD16(Kg + (size_t)(kv0 + krow) * 128 + ((g ^ (krow & 7)) * 8),
            Klds + (w * 128 + i * 64) * 8);
    }
#pragma unroll
    for (int i = 0; i < 2; ++i) {
      int c = w * 128 + i * 64 + lane;
      int d = c >> 3, g = c & 7;
      GLD16(Vg + (size_t)d * 1024 + kv0 + ((g ^ (d & 7)) * 8),
            Vlds + (w * 128 + i * 64) * 8);
    }
    __syncthreads();

    f32x4 s[4] = {};
#pragma unroll
    for (int kc = 0; kc < 4; ++kc) {
#pragma unroll
      for (int n = 0; n < 4; ++n) {
        int kv = n * 16 + l16;
        int g = kc * 4 + lhi;
        bf16x8 bk = *(const bf16x8*)(Klds + kv * 128 + ((g ^ (kv & 7)) * 8));
        s[n] = mfma16(aq[kc], bk, s[n]);
      }
    }
    if (kv0 + 63 > qmin) {
#pragma unroll
      for (int n = 0; n < 4; ++n)
#pragma unroll
        for (int r = 0; r < 4; ++r) {
          int q = qmin + lhi * 4 + r;
          int kv = kv0 + n * 16 + l16;
          if (kv > q) s[n][r] = -1e30f;
        }
    }
    float pr[4][4];
#pragma unroll
    for (int r = 0; r < 4; ++r) {
      float mx = fmaxf(fmaxf(s[0][r], s[1][r]), fmaxf(s[2][r], s[3][r]));
      mx = fmaxf(mx, __shfl_xor(mx, 1));
      mx = fmaxf(mx, __shfl_xor(mx, 2));
      mx = fmaxf(mx, __shfl_xor(mx, 4));
      mx = fmaxf(mx, __shfl_xor(mx, 8));
      float mn = fmaxf(m_run[r], mx);
      float sf = __expf(m_run[r] - mn);
      m_run[r] = mn;
      float sum = 0.f;
#pragma unroll
      for (int n = 0; n < 4; ++n) {
        float p = __expf(s[n][r] - mn);
        pr[n][r] = p;
        sum += p;
      }
      sum += __shfl_xor(sum, 1);
      sum += __shfl_xor(sum, 2);
      sum += __shfl_xor(sum, 4);
      sum += __shfl_xor(sum, 8);
      l_run[r] = l_run[r] * sf + sum;
#pragma unroll
      for (int nd = 0; nd < 8; ++nd) o[nd][r] *= sf;
    }
    u16* pw = Plds + w * 1152;
#pragma unroll
    for (int n = 0; n < 4; ++n)
#pragma unroll
      for (int r = 0; r < 4; ++r) pw[(lhi * 4 + r) * 72 + n * 16 + l16] = f2b(pr[n][r]);
#pragma unroll
    for (int kc = 0; kc < 2; ++kc) {
      bf16x8 ap = *(const bf16x8*)(pw + l16 * 72 + kc * 32 + lhi * 8);
#pragma unroll
      for (int nd = 0; nd < 8; ++nd) {
        int d = nd * 16 + l16;
        int g = kc * 4 + lhi;
        bf16x8 bv = *(const bf16x8*)(Vlds + d * 64 + ((g ^ (d & 7)) * 8));
        o[nd] = mfma16(ap, bv, o[nd]);
      }
    }
    __syncthreads();
  }
#pragma unroll
  for (int r = 0; r < 4; ++r) {
    float inv = 1.0f / l_run[r];
    int q = qmin + lhi * 4 + r;
    u16* orow = ao + ((size_t)(b * 1024 + q)) * 4096 + h * 128;
#pragma unroll
    for (int nd = 0; nd < 8; ++nd) orow[nd * 16 + l16] = f2b(o[nd][r] * inv);
  }
}

extern "C" void kernel_launch(void* const* d_in, const int* in_sizes, int n_in,
                              void* d_out, int out_size, void* d_ws, size_t ws_size,
                              hipStream_t stream) {
  const float* x = (const float*)d_in[0];
  const float* wq = (const float*)d_in[2];
  const float* wk = (const float*)d_in[3];
  const float* wv = (const float*)d_in[4];
  const float* wo = (const float*)d_in[5];

  char* ws = (char*)d_ws;
  u16* xb = (u16*)(ws + 0);
  u16* wcat = (u16*)(ws + 33554432);
  u16* qr = (u16*)(ws + 0);
  u16* kr = (u16*)(ws + 33554432);
  u16* vrt = (u16*)(ws + 41943040);
  u16* ao = (u16*)(ws + 50331648);
  u16* wob = (u16*)(ws + 83886080);
  float2* tab = (float2*)(ws + 117440512);
  u16* qkv = (u16*)d_out;

  hipFuncSetAttribute((const void*)k_gemm8<u16>,
                      hipFuncAttributeMaxDynamicSharedMemorySize, 131072);
  hipFuncSetAttribute((const void*)k_gemm8<float>,
                      hipFuncAttributeMaxDynamicSharedMemorySize, 131072);

  k_rope_table<<<256, 256, 0, stream>>>(tab);
  k_cast8<<<8192, 256, 0, stream>>>(x, xb);
  k_tcast<<<4096, 256, 0, stream>>>(wq, wcat, 4096, 4096);
  k_tcast<<<1024, 256, 0, stream>>>(wk, wcat + (size_t)4096 * 4096, 4096, 1024);
  k_tcast<<<1024, 256, 0, stream>>>(wv, wcat + (size_t)5120 * 4096, 4096, 1024);
  k_tcast<<<4096, 256, 0, stream>>>(wo, wob, 4096, 4096);
  k_gemm8<u16><<<384, 512, 131072, stream>>>(xb, wcat, qkv, 4096, 6144, 4096);
  k_rope<<<40960, 256, 0, stream>>>(qkv, tab, qr, kr);
  k_vtrans<<<1024, 256, 0, stream>>>(qkv, vrt);
  k_attn<<<1024, 512, 0, stream>>>(qr, kr, vrt, ao);
  k_gemm8<float><<<256, 512, 131072, stream>>>(ao, wob, (float*)d_out, 4096, 4096, 4096);
}

// Round 8
// 632.654 us; speedup vs baseline: 1.4042x; 1.4042x over previous
//
#include <hip/hip_runtime.h>
#include <stdint.h>

typedef unsigned short u16;
typedef __bf16 bf16x8 __attribute__((ext_vector_type(8)));
typedef float f32x4 __attribute__((ext_vector_type(4)));

__device__ __forceinline__ u16 f2b(float x) {
  uint32_t b = __float_as_uint(x);
  b += 0x7fff + ((b >> 16) & 1);
  return (u16)(b >> 16);
}
__device__ __forceinline__ float b2f(u16 u) {
  return __uint_as_float(((uint32_t)u) << 16);
}

#define GLD16(src, dst)                                                                  \
  __builtin_amdgcn_global_load_lds((const __attribute__((address_space(1))) void*)(src),\
                                   (__attribute__((address_space(3))) void*)(dst), 16, 0, 0)

__device__ __forceinline__ f32x4 mfma16(bf16x8 a, bf16x8 b, f32x4 c) {
  return __builtin_amdgcn_mfma_f32_16x16x32_bf16(a, b, c, 0, 0, 0);
}

// ---------------- RoPE cos/sin table
__global__ void k_rope_table(float2* __restrict__ tab) {
  int i = blockIdx.x * 256 + threadIdx.x;  // 65536 = 1024 * 64
  int l = i >> 6, d = i & 63;
  float inv = powf(10000.0f, -(float)(2 * d) / 128.0f);
  float ang = (float)l * inv;
  float s, c;
  sincosf(ang, &s, &c);
  tab[i] = make_float2(c, s);
}

// ---------------- fp32 -> bf16 cast, 8 elems/thread
__global__ void k_cast8(const float* __restrict__ src, u16* __restrict__ dst) {
  size_t i = (size_t)blockIdx.x * 256 + threadIdx.x;
  const float4* s4 = (const float4*)src;
  float4 a = s4[2 * i], b = s4[2 * i + 1];
  union { u16 u[8]; uint4 v; } o;
  o.u[0] = f2b(a.x); o.u[1] = f2b(a.y); o.u[2] = f2b(a.z); o.u[3] = f2b(a.w);
  o.u[4] = f2b(b.x); o.u[5] = f2b(b.y); o.u[6] = f2b(b.z); o.u[7] = f2b(b.w);
  ((uint4*)dst)[i] = o.v;
}

// ---------------- transpose-cast: src fp32 [R][C] -> dst bf16 [C][R]
__global__ __launch_bounds__(256) void k_tcast(const float* __restrict__ src,
                                               u16* __restrict__ dst, int R, int C) {
  __shared__ u16 t[64][72];
  int tiles_c = C >> 6;
  int tr = blockIdx.x / tiles_c, tc = blockIdx.x % tiles_c;
  int tid = threadIdx.x;
  {
    int rr = tid >> 4, cv = tid & 15;
#pragma unroll
    for (int it = 0; it < 4; ++it) {
      int row = rr + it * 16;
      float4 v = *(const float4*)(src + (size_t)(tr * 64 + row) * C + tc * 64 + cv * 4);
      t[row][cv * 4 + 0] = f2b(v.x);
      t[row][cv * 4 + 1] = f2b(v.y);
      t[row][cv * 4 + 2] = f2b(v.z);
      t[row][cv * 4 + 3] = f2b(v.w);
    }
  }
  __syncthreads();
  {
    int cc = tid >> 3, g = tid & 7;
#pragma unroll
    for (int it = 0; it < 2; ++it) {
      int c = cc + it * 32;
      union { u16 u[8]; uint4 v; } o;
#pragma unroll
      for (int j = 0; j < 8; ++j) o.u[j] = t[g * 8 + j][c];
      *(uint4*)(dst + (size_t)(tc * 64 + c) * R + tr * 64 + g * 8) = o.v;
    }
  }
}

// ---------------- V transpose
__global__ __launch_bounds__(256) void k_vtrans(const u16* __restrict__ qkv,
                                                u16* __restrict__ vrt) {
  __shared__ u16 t[64][72];
  int b = blockIdx.x >> 8;
  int tt = blockIdx.x & 255;
  int tr = tt >> 4, tc = tt & 15;
  int tid = threadIdx.x;
  {
    int rr = tid >> 3, g = tid & 7;
#pragma unroll
    for (int it = 0; it < 2; ++it) {
      int row = rr + it * 32;
      union { u16 u[8]; uint4 v; } o;
      o.v = *(const uint4*)(qkv + (size_t)(b * 1024 + tr * 64 + row) * 6144 + 5120 + tc * 64 + g * 8);
#pragma unroll
      for (int j = 0; j < 8; ++j) t[row][g * 8 + j] = o.u[j];
    }
  }
  __syncthreads();
  {
    int cc = tid >> 3, g = tid & 7;
#pragma unroll
    for (int it = 0; it < 2; ++it) {
      int c = cc + it * 32;
      union { u16 u[8]; uint4 v; } o;
#pragma unroll
      for (int j = 0; j < 8; ++j) o.u[j] = t[g * 8 + j][c];
      *(uint4*)(vrt + (size_t)(b * 1024 + tc * 64 + c) * 1024 + tr * 64 + g * 8) = o.v;
    }
  }
}

// ---------------- RoPE scatter
__global__ void k_rope(const u16* __restrict__ qkv, const float2* __restrict__ tab,
                       u16* __restrict__ qr, u16* __restrict__ kr) {
  int u = blockIdx.x * 256 + threadIdx.x;  // 4096 * 2560
  int row = u / 2560;
  int j = u - row * 2560;
  int b = row >> 10, l = row & 1023;
  const float scale = 0.08838834764831845f;  // 128^-0.5
  if (j < 2048) {
    int h = j >> 6, dp = j & 63;
    uint32_t pair = *(const uint32_t*)(qkv + (size_t)row * 6144 + h * 128 + 2 * dp);
    float2 cs = tab[l * 64 + dp];
    float x1 = b2f((u16)pair), x2 = b2f((u16)(pair >> 16));
    float r1 = (x1 * cs.x - x2 * cs.y) * scale;
    float r2 = (x1 * cs.y + x2 * cs.x) * scale;
    uint32_t outw = (uint32_t)f2b(r1) | ((uint32_t)f2b(r2) << 16);
    *(uint32_t*)(qr + ((size_t)((b * 32 + h) * 1024 + l)) * 128 + 2 * dp) = outw;
  } else {
    int jj = j - 2048;
    int kh = jj >> 6, dp = jj & 63;
    uint32_t pair = *(const uint32_t*)(qkv + (size_t)row * 6144 + 4096 + kh * 128 + 2 * dp);
    float2 cs = tab[l * 64 + dp];
    float x1 = b2f((u16)pair), x2 = b2f((u16)(pair >> 16));
    float r1 = x1 * cs.x - x2 * cs.y;
    float r2 = x1 * cs.y + x2 * cs.x;
    uint32_t outw = (uint32_t)f2b(r1) | ((uint32_t)f2b(r2) << 16);
    *(uint32_t*)(kr + ((size_t)((b * 8 + kh) * 1024 + l)) * 128 + 2 * dp) = outw;
  }
}

// ================= 256x256 8-phase bf16 GEMM, 4-WAVE read-ahead-1 pipeline =================
// R7->R8: same verified schedule, but 4 waves (256 thr), wave-tile 128x128.
// WHY: per-SIMD RF physics (m69: waves/CU halve at 64/128/256 VGPR) => 8-wave
// blocks (2 waves/EU) cap at 256 regs/wave TOTAL; acc=128 AGPR left only 128
// arch VGPRs -> the 4 fragment sets (+64) could never fit (R5-R7 spills).
// 4 waves @ waves_per_eu(1,1) => 512 regs/wave: acc 256 + frags ~96 + addr ~40.
// Side benefits: LDS read traffic per tile 192KB->128KB (bigger wave tile =
// better reuse; model ceiling ~85%), out-proj grid = 256 = 1 perfect round.
// Mechanical deltas: STAGE = 4 GLDs/thread (256 thr x 4 x 16B = 16KB half-tile),
// so counted waits become vmcnt(12) (= 3 newest half-tiles x 4 loads in flight;
// same invariant as the verified vmcnt(6) with 2 loads/stage).
// LDS layout and XOR-granule swizzle identical to R4 (bank-conflict 0).

#define STAGE(sbase, koff, ldsoff)                        \
  GLD16((sbase) + (koff), dstp + (ldsoff));               \
  GLD16((sbase) + (koff) + K64, dstp + (ldsoff) + 2048);  \
  GLD16((sbase) + (koff) + 2 * K64, dstp + (ldsoff) + 4096); \
  GLD16((sbase) + (koff) + 3 * K64, dstp + (ldsoff) + 6144);

#define LOADB(dst, base, kh)                                              \
  dst[0] = *(const bf16x8*)((base) + (kh) * 8192 + 0 * 512);              \
  dst[1] = *(const bf16x8*)((base) + (kh) * 8192 + 1 * 512);              \
  dst[2] = *(const bf16x8*)((base) + (kh) * 8192 + 2 * 512);              \
  dst[3] = *(const bf16x8*)((base) + (kh) * 8192 + 3 * 512);              \
  dst[4] = *(const bf16x8*)((base) + (kh) * 8192 + 4 * 512);              \
  dst[5] = *(const bf16x8*)((base) + (kh) * 8192 + 5 * 512);              \
  dst[6] = *(const bf16x8*)((base) + (kh) * 8192 + 6 * 512);              \
  dst[7] = *(const bf16x8*)((base) + (kh) * 8192 + 7 * 512);

#define LOADA(dst, base, kh, mh)                                          \
  dst[0] = *(const bf16x8*)((base) + (kh) * 8192 + (mh) * 2048 + 0 * 512);\
  dst[1] = *(const bf16x8*)((base) + (kh) * 8192 + (mh) * 2048 + 1 * 512);\
  dst[2] = *(const bf16x8*)((base) + (kh) * 8192 + (mh) * 2048 + 2 * 512);\
  dst[3] = *(const bf16x8*)((base) + (kh) * 8192 + (mh) * 2048 + 3 * 512);

#define MFMA_PHASE(mh, AF, BF)                                            \
  asm volatile("s_waitcnt lgkmcnt(0)" ::: "memory");                      \
  __builtin_amdgcn_sched_barrier(0);                                      \
  __builtin_amdgcn_s_setprio(1);                                          \
  _Pragma("unroll") for (int mm = 0; mm < 4; ++mm)                        \
    _Pragma("unroll") for (int n_ = 0; n_ < 8; ++n_)                      \
      acc[(mh) * 4 + mm][n_] = mfma16(AF[mm], BF[n_], acc[(mh) * 4 + mm][n_]); \
  __builtin_amdgcn_s_setprio(0);                                          \
  __builtin_amdgcn_sched_barrier(0);

#define ENDP __builtin_amdgcn_s_barrier();

template <typename OutT>
__global__ __launch_bounds__(256)
__attribute__((amdgpu_waves_per_eu(1, 1)))
void k_gemm8(const u16* __restrict__ A,
             const u16* __restrict__ Bt,
             OutT* __restrict__ C,
             int M, int N, int K) {
  extern __shared__ u16 lds[];
  const int tid = threadIdx.x;
  const int lane = tid & 63, wid = tid >> 6;      // 4 waves
  const int l16 = lane & 15, lhi = lane >> 4;
  const int wm = wid >> 1, wn = wid & 1;          // 2M x 2N, 128x128 per wave

  const int nbn = N >> 8;
  int bid = blockIdx.x;
  const int cpx = gridDim.x >> 3;
  bid = (bid & 7) * cpx + (bid >> 3);  // XCD swizzle (grid % 8 == 0)
  const int bm = (bid / nbn) << 8;
  const int bn = (bid % nbn) << 8;

  const u16* Ag = A + (size_t)bm * K;
  const u16* Bg = Bt + (size_t)bn * K;
  const size_t K64 = (size_t)64 * K;

  // ---- per-thread constant addresses ----
  const int swz = (lhi ^ ((l16 >> 1) & 3)) << 3;      // lane-constant swizzle
  const u16* pA0 = lds + wm * 4096 + l16 * 32 + swz;           // A reads, buf0
  const u16* pA1 = pA0 + 32768;                                // A reads, buf1
  const u16* pB0 = lds + 16384 + wn * 4096 + l16 * 32 + swz;   // B reads, buf0
  const u16* pB1 = pB0 + 32768;                                // B reads, buf1

  const int r0 = tid >> 2, g0 = tid & 3;     // stage rows: r0 + i*64, i=0..3
  const size_t so = (size_t)r0 * K + ((g0 ^ ((r0 >> 1) & 3)) << 3);
  const u16* sA = Ag + so;
  const u16* sB = Bg + so;
  u16* dstp = lds + tid * 8;  // chunk (i*256+tid) lands at lds[(i*256+tid)*8]

  f32x4 acc[8][8] = {};
  bf16x8 afrA[4], afrB[4], bfrA[8], bfrB[8];

  // ---- prologue: tile0 (buf0) fully; tile1 (buf1) B-k0, A-k0, B-k1
  STAGE(sA, 0, 0);            // A t0 kh0
  STAGE(sA, 32, 8192);        // A t0 kh1
  STAGE(sB, 0, 16384);        // B t0 kh0
  STAGE(sB, 32, 24576);       // B t0 kh1
  STAGE(sB, 64, 49152);       // B t1 kh0
  STAGE(sA, 64, 32768);       // A t1 kh0
  STAGE(sB, 96, 57344);       // B t1 kh1
  asm volatile("s_waitcnt vmcnt(12)" ::: "memory");
  __builtin_amdgcn_s_barrier();
  // pre-load P1 fragments (tile0, kh0, mh0)
  LOADB(bfrA, pB0, 0)
  LOADA(afrA, pA0, 0, 0)

  const int nt = K >> 6;
  for (int t = 0; t < nt; t += 2) {
    const bool more = (t + 2) < nt;
    const int kA1 = (t + 1) * 64 + 32;
    const int k2 = (t + 2) * 64;
    const int k3 = (t + 3) * 64;
    // P1: MFMA t kh0 mh0 | read P2 frags; stage A-k1(t+1)->buf1
    MFMA_PHASE(0, afrA, bfrA)
    LOADA(afrB, pA0, 0, 1)
    STAGE(sA, kA1, 40960);
    ENDP
    // P2: MFMA t kh0 mh1 | read P3 frags; stage B-k0(t+2)->buf0
    MFMA_PHASE(1, afrB, bfrA)
    LOADB(bfrB, pB0, 1)
    LOADA(afrA, pA0, 1, 0)
    if (more) { STAGE(sB, k2, 16384); }
    ENDP
    // P3: MFMA t kh1 mh0 | read P4 frags; stage A-k0(t+2)->buf0
    MFMA_PHASE(0, afrA, bfrB)
    LOADA(afrB, pA0, 1, 1)
    if (more) { STAGE(sA, k2, 0); }
    ENDP
    // P4: MFMA t kh1 mh1 | stage B-k1(t+2); vmcnt; read P5 frags (tile t+1)
    MFMA_PHASE(1, afrB, bfrB)
    if (more) {
      STAGE(sB, k2 + 32, 24576);
      asm volatile("s_waitcnt vmcnt(12)" ::: "memory");
    } else {
      asm volatile("s_waitcnt vmcnt(0)" ::: "memory");
    }
    LOADB(bfrA, pB1, 0)
    LOADA(afrA, pA1, 0, 0)
    ENDP
    // P5: MFMA t+1 kh0 mh0 | read P6 frags; stage A-k1(t+2)->buf0
    MFMA_PHASE(0, afrA, bfrA)
    LOADA(afrB, pA1, 0, 1)
    if (more) { STAGE(sA, k2 + 32, 8192); }
    ENDP
    // P6: MFMA t+1 kh0 mh1 | read P7 frags; stage B-k0(t+3)->buf1
    MFMA_PHASE(1, afrB, bfrA)
    LOADB(bfrB, pB1, 1)
    LOADA(afrA, pA1, 1, 0)
    if (more) { STAGE(sB, k3, 49152); }
    ENDP
    // P7: MFMA t+1 kh1 mh0 | read P8 frags; stage A-k0(t+3)->buf1
    MFMA_PHASE(0, afrA, bfrB)
    LOADA(afrB, pA1, 1, 1)
    if (more) { STAGE(sA, k3, 32768); }
    ENDP
    // P8: MFMA t+1 kh1 mh1 | stage B-k1(t+3); vmcnt; read next-P1 frags
    MFMA_PHASE(1, afrB, bfrB)
    if (more) {
      STAGE(sB, k3 + 32, 57344);
      asm volatile("s_waitcnt vmcnt(12)" ::: "memory");
      LOADB(bfrA, pB0, 0)
      LOADA(afrA, pA0, 0, 0)
    }
    ENDP
  }

  // ---- epilogue: C write
#pragma unroll
  for (int m = 0; m < 8; ++m) {
    int row = bm + wm * 128 + m * 16 + lhi * 4;
#pragma unroll
    for (int n = 0; n < 8; ++n) {
      int col = bn + wn * 128 + n * 16 + l16;
#pragma unroll
      for (int r = 0; r < 4; ++r) {
        float v = acc[m][n][r];
        size_t idx = (size_t)(row + r) * N + col;
        if constexpr (sizeof(OutT) == 2) C[idx] = f2b(v);
        else C[idx] = v;
      }
    }
  }
}

// ---------------- flash attention (unchanged)
__global__ __launch_bounds__(512) void k_attn(const u16* __restrict__ qr,
                                              const u16* __restrict__ kr,
                                              const u16* __restrict__ vrt,
                                              u16* __restrict__ ao) {
  __shared__ u16 Klds[8192];
  __shared__ u16 Vlds[8192];
  __shared__ u16 Plds[9216];
  int bid = blockIdx.x;
  int qb = bid & 7, h = (bid >> 3) & 31, b = bid >> 8;
  int kvh = h & 7;
  int lane = threadIdx.x & 63, w = threadIdx.x >> 6;
  int l16 = lane & 15, lhi = lane >> 4;
  int qmin = qb * 128 + w * 16;

  const u16* qbase = qr + ((size_t)((b * 32 + h) * 1024) + qmin + l16) * 128;
  bf16x8 aq[4];
#pragma unroll
  for (int kc = 0; kc < 4; ++kc) aq[kc] = *(const bf16x8*)(qbase + kc * 32 + lhi * 8);

  const u16* Kg = kr + (size_t)(b * 8 + kvh) * (1024 * 128);
  const u16* Vg = vrt + (size_t)(b * 8 + kvh) * (128 * 1024);

  float m_run[4] = {-1e30f, -1e30f, -1e30f, -1e30f};
  float l_run[4] = {0.f, 0.f, 0.f, 0.f};
  f32x4 o[8] = {};

  int nkb = 2 * qb + 2;
  for (int kb = 0; kb < nkb; ++kb) {
    int kv0 = kb * 64;
#pragma unroll
    for (int i = 0; i < 2; ++i) {
      int c = w * 128 + i * 64 + lane;
      int krow = c >> 4, g = c & 15;
      GLD16(Kg + (size_t)(kv0 + krow) * 128 + ((g ^ (krow & 7)) * 8),
            Klds + (w * 128 + i * 64) * 8);
    }
#pragma unroll
    for (int i = 0; i < 2; ++i) {
      int c = w * 128 + i * 64 + lane;
      int d = c >> 3, g = c & 7;
      GLD16(Vg + (size_t)d * 1024 + kv0 + ((g ^ (d & 7)) * 8),
            Vlds + (w * 128 + i * 64) * 8);
    }
    __syncthreads();

    f32x4 s[4] = {};
#pragma unroll
    for (int kc = 0; kc < 4; ++kc) {
#pragma unroll
      for (int n = 0; n < 4; ++n) {
        int kv = n * 16 + l16;
        int g = kc * 4 + lhi;
        bf16x8 bk = *(const bf16x8*)(Klds + kv * 128 + ((g ^ (kv & 7)) * 8));
        s[n] = mfma16(aq[kc], bk, s[n]);
      }
    }
    if (kv0 + 63 > qmin) {
#pragma unroll
      for (int n = 0; n < 4; ++n)
#pragma unroll
        for (int r = 0; r < 4; ++r) {
          int q = qmin + lhi * 4 + r;
          int kv = kv0 + n * 16 + l16;
          if (kv > q) s[n][r] = -1e30f;
        }
    }
    float pr[4][4];
#pragma unroll
    for (int r = 0; r < 4; ++r) {
      float mx = fmaxf(fmaxf(s[0][r], s[1][r]), fmaxf(s[2][r], s[3][r]));
      mx = fmaxf(mx, __shfl_xor(mx, 1));
      mx = fmaxf(mx, __shfl_xor(mx, 2));
      mx = fmaxf(mx, __shfl_xor(mx, 4));
      mx = fmaxf(mx, __shfl_xor(mx, 8));
      float mn = fmaxf(m_run[r], mx);
      float sf = __expf(m_run[r] - mn);
      m_run[r] = mn;
      float sum = 0.f;
#pragma unroll
      for (int n = 0; n < 4; ++n) {
        float p = __expf(s[n][r] - mn);
        pr[n][r] = p;
        sum += p;
      }
      sum += __shfl_xor(sum, 1);
      sum += __shfl_xor(sum, 2);
      sum += __shfl_xor(sum, 4);
      sum += __shfl_xor(sum, 8);
      l_run[r] = l_run[r] * sf + sum;
#pragma unroll
      for (int nd = 0; nd < 8; ++nd) o[nd][r] *= sf;
    }
    u16* pw = Plds + w * 1152;
#pragma unroll
    for (int n = 0; n < 4; ++n)
#pragma unroll
      for (int r = 0; r < 4; ++r) pw[(lhi * 4 + r) * 72 + n * 16 + l16] = f2b(pr[n][r]);
#pragma unroll
    for (int kc = 0; kc < 2; ++kc) {
      bf16x8 ap = *(const bf16x8*)(pw + l16 * 72 + kc * 32 + lhi * 8);
#pragma unroll
      for (int nd = 0; nd < 8; ++nd) {
        int d = nd * 16 + l16;
        int g = kc * 4 + lhi;
        bf16x8 bv = *(const bf16x8*)(Vlds + d * 64 + ((g ^ (d & 7)) * 8));
        o[nd] = mfma16(ap, bv, o[nd]);
      }
    }
    __syncthreads();
  }
#pragma unroll
  for (int r = 0; r < 4; ++r) {
    float inv = 1.0f / l_run[r];
    int q = qmin + lhi * 4 + r;
    u16* orow = ao + ((size_t)(b * 1024 + q)) * 4096 + h * 128;
#pragma unroll
    for (int nd = 0; nd < 8; ++nd) orow[nd * 16 + l16] = f2b(o[nd][r] * inv);
  }
}

extern "C" void kernel_launch(void* const* d_in, const int* in_sizes, int n_in,
                              void* d_out, int out_size, void* d_ws, size_t ws_size,
                              hipStream_t stream) {
  const float* x = (const float*)d_in[0];
  const float* wq = (const float*)d_in[2];
  const float* wk = (const float*)d_in[3];
  const float* wv = (const float*)d_in[4];
  const float* wo = (const float*)d_in[5];

  char* ws = (char*)d_ws;
  u16* xb = (u16*)(ws + 0);
  u16* wcat = (u16*)(ws + 33554432);
  u16* qr = (u16*)(ws + 0);
  u16* kr = (u16*)(ws + 33554432);
  u16* vrt = (u16*)(ws + 41943040);
  u16* ao = (u16*)(ws + 50331648);
  u16* wob = (u16*)(ws + 83886080);
  float2* tab = (float2*)(ws + 117440512);
  u16* qkv = (u16*)d_out;

  hipFuncSetAttribute((const void*)k_gemm8<u16>,
                      hipFuncAttributeMaxDynamicSharedMemorySize, 131072);
  hipFuncSetAttribute((const void*)k_gemm8<float>,
                      hipFuncAttributeMaxDynamicSharedMemorySize, 131072);

  k_rope_table<<<256, 256, 0, stream>>>(tab);
  k_cast8<<<8192, 256, 0, stream>>>(x, xb);
  k_tcast<<<4096, 256, 0, stream>>>(wq, wcat, 4096, 4096);
  k_tcast<<<1024, 256, 0, stream>>>(wk, wcat + (size_t)4096 * 4096, 4096, 1024);
  k_tcast<<<1024, 256, 0, stream>>>(wv, wcat + (size_t)5120 * 4096, 4096, 1024);
  k_tcast<<<4096, 256, 0, stream>>>(wo, wob, 4096, 4096);
  k_gemm8<u16><<<384, 256, 131072, stream>>>(xb, wcat, qkv, 4096, 6144, 4096);
  k_rope<<<40960, 256, 0, stream>>>(qkv, tab, qr, kr);
  k_vtrans<<<1024, 256, 0, stream>>>(qkv, vrt);
  k_attn<<<1024, 512, 0, stream>>>(qr, kr, vrt, ao);
  k_gemm8<float><<<256, 256, 131072, stream>>>(ao, wob, (float*)d_out, 4096, 4096, 4096);
}

// Round 9
// 554.804 us; speedup vs baseline: 1.6013x; 1.1403x over previous
//
#include <hip/hip_runtime.h>
#include <stdint.h>

typedef unsigned short u16;
typedef __bf16 bf16x8 __attribute__((ext_vector_type(8)));
typedef float f32x4 __attribute__((ext_vector_type(4)));

__device__ __forceinline__ u16 f2b(float x) {
  uint32_t b = __float_as_uint(x);
  b += 0x7fff + ((b >> 16) & 1);
  return (u16)(b >> 16);
}
__device__ __forceinline__ float b2f(u16 u) {
  return __uint_as_float(((uint32_t)u) << 16);
}

#define GLD16(src, dst)                                                                  \
  __builtin_amdgcn_global_load_lds((const __attribute__((address_space(1))) void*)(src),\
                                   (__attribute__((address_space(3))) void*)(dst), 16, 0, 0)

__device__ __forceinline__ f32x4 mfma16(bf16x8 a, bf16x8 b, f32x4 c) {
  return __builtin_amdgcn_mfma_f32_16x16x32_bf16(a, b, c, 0, 0, 0);
}

// ---------------- RoPE cos/sin table
__global__ void k_rope_table(float2* __restrict__ tab) {
  int i = blockIdx.x * 256 + threadIdx.x;  // 65536 = 1024 * 64
  int l = i >> 6, d = i & 63;
  float inv = powf(10000.0f, -(float)(2 * d) / 128.0f);
  float ang = (float)l * inv;
  float s, c;
  sincosf(ang, &s, &c);
  tab[i] = make_float2(c, s);
}

// ---------------- fp32 -> bf16 cast, 8 elems/thread
__global__ void k_cast8(const float* __restrict__ src, u16* __restrict__ dst) {
  size_t i = (size_t)blockIdx.x * 256 + threadIdx.x;
  const float4* s4 = (const float4*)src;
  float4 a = s4[2 * i], b = s4[2 * i + 1];
  union { u16 u[8]; uint4 v; } o;
  o.u[0] = f2b(a.x); o.u[1] = f2b(a.y); o.u[2] = f2b(a.z); o.u[3] = f2b(a.w);
  o.u[4] = f2b(b.x); o.u[5] = f2b(b.y); o.u[6] = f2b(b.z); o.u[7] = f2b(b.w);
  ((uint4*)dst)[i] = o.v;
}

// ---------------- transpose-cast: src fp32 [R][C] -> dst bf16 [C][R]
__global__ __launch_bounds__(256) void k_tcast(const float* __restrict__ src,
                                               u16* __restrict__ dst, int R, int C) {
  __shared__ u16 t[64][72];
  int tiles_c = C >> 6;
  int tr = blockIdx.x / tiles_c, tc = blockIdx.x % tiles_c;
  int tid = threadIdx.x;
  {
    int rr = tid >> 4, cv = tid & 15;
#pragma unroll
    for (int it = 0; it < 4; ++it) {
      int row = rr + it * 16;
      float4 v = *(const float4*)(src + (size_t)(tr * 64 + row) * C + tc * 64 + cv * 4);
      t[row][cv * 4 + 0] = f2b(v.x);
      t[row][cv * 4 + 1] = f2b(v.y);
      t[row][cv * 4 + 2] = f2b(v.z);
      t[row][cv * 4 + 3] = f2b(v.w);
    }
  }
  __syncthreads();
  {
    int cc = tid >> 3, g = tid & 7;
#pragma unroll
    for (int it = 0; it < 2; ++it) {
      int c = cc + it * 32;
      union { u16 u[8]; uint4 v; } o;
#pragma unroll
      for (int j = 0; j < 8; ++j) o.u[j] = t[g * 8 + j][c];
      *(uint4*)(dst + (size_t)(tc * 64 + c) * R + tr * 64 + g * 8) = o.v;
    }
  }
}

// ---------------- V transpose
__global__ __launch_bounds__(256) void k_vtrans(const u16* __restrict__ qkv,
                                                u16* __restrict__ vrt) {
  __shared__ u16 t[64][72];
  int b = blockIdx.x >> 8;
  int tt = blockIdx.x & 255;
  int tr = tt >> 4, tc = tt & 15;
  int tid = threadIdx.x;
  {
    int rr = tid >> 3, g = tid & 7;
#pragma unroll
    for (int it = 0; it < 2; ++it) {
      int row = rr + it * 32;
      union { u16 u[8]; uint4 v; } o;
      o.v = *(const uint4*)(qkv + (size_t)(b * 1024 + tr * 64 + row) * 6144 + 5120 + tc * 64 + g * 8);
#pragma unroll
      for (int j = 0; j < 8; ++j) t[row][g * 8 + j] = o.u[j];
    }
  }
  __syncthreads();
  {
    int cc = tid >> 3, g = tid & 7;
#pragma unroll
    for (int it = 0; it < 2; ++it) {
      int c = cc + it * 32;
      union { u16 u[8]; uint4 v; } o;
#pragma unroll
      for (int j = 0; j < 8; ++j) o.u[j] = t[g * 8 + j][c];
      *(uint4*)(vrt + (size_t)(b * 1024 + tc * 64 + c) * 1024 + tr * 64 + g * 8) = o.v;
    }
  }
}

// ---------------- RoPE scatter
__global__ void k_rope(const u16* __restrict__ qkv, const float2* __restrict__ tab,
                       u16* __restrict__ qr, u16* __restrict__ kr) {
  int u = blockIdx.x * 256 + threadIdx.x;  // 4096 * 2560
  int row = u / 2560;
  int j = u - row * 2560;
  int b = row >> 10, l = row & 1023;
  const float scale = 0.08838834764831845f;  // 128^-0.5
  if (j < 2048) {
    int h = j >> 6, dp = j & 63;
    uint32_t pair = *(const uint32_t*)(qkv + (size_t)row * 6144 + h * 128 + 2 * dp);
    float2 cs = tab[l * 64 + dp];
    float x1 = b2f((u16)pair), x2 = b2f((u16)(pair >> 16));
    float r1 = (x1 * cs.x - x2 * cs.y) * scale;
    float r2 = (x1 * cs.y + x2 * cs.x) * scale;
    uint32_t outw = (uint32_t)f2b(r1) | ((uint32_t)f2b(r2) << 16);
    *(uint32_t*)(qr + ((size_t)((b * 32 + h) * 1024 + l)) * 128 + 2 * dp) = outw;
  } else {
    int jj = j - 2048;
    int kh = jj >> 6, dp = jj & 63;
    uint32_t pair = *(const uint32_t*)(qkv + (size_t)row * 6144 + 4096 + kh * 128 + 2 * dp);
    float2 cs = tab[l * 64 + dp];
    float x1 = b2f((u16)pair), x2 = b2f((u16)(pair >> 16));
    float r1 = x1 * cs.x - x2 * cs.y;
    float r2 = x1 * cs.y + x2 * cs.x;
    uint32_t outw = (uint32_t)f2b(r1) | ((uint32_t)f2b(r2) << 16);
    *(uint32_t*)(kr + ((size_t)((b * 8 + kh) * 1024 + l)) * 128 + 2 * dp) = outw;
  }
}

// ================= 256x256 8-phase bf16 GEMM (R4 structure, de-pinned + peeled) =================
// C[M][N] = A[M][K] * Bt[N][K]^T.  512 thr / 8 waves (2M x 4N), BK=64, 128KiB LDS.
// Addressing / swizzle / stage order / vmcnt placement IDENTICAL to R4 (verified,
// bank-conflict 0, no spill at VGPR 116). R8->R9 changes, per m141/m196/m201:
//  (1) NO sched_barrier(0) pins -- m141 measured order-pinning as 874->510 TF;
//      m201's 62%-util template has none. ds_reads are IR-visible loads, so the
//      compiler's dependency tracking prevents MFMA-above-def hoisting (rule #18
//      applies only to inline-asm ds_reads). Compiler is free to interleave
//      address calc / GLD issue / MFMA (the m196 lever).
//  (2) Steady loop is branch-free (stages unconditional); last 2 K-tiles peeled
//      into an explicit tail -- no if(more) basic-block splits.
// Phase skeleton (= m201): loads; stage; [vmcnt@P4/P8]; s_barrier; lgkmcnt(0);
// setprio(1); 16 MFMA; setprio(0); s_barrier.

#define STAGE2(s0, s1, koff, ldsoff)          \
  GLD16((s0) + (koff), dst0 + (ldsoff));      \
  GLD16((s1) + (koff), dst1 + (ldsoff));

#define LOADB(base, kh)                                                   \
  bfr[0] = *(const bf16x8*)((base) + (kh) * 8192 + 0 * 512);              \
  bfr[1] = *(const bf16x8*)((base) + (kh) * 8192 + 1 * 512);              \
  bfr[2] = *(const bf16x8*)((base) + (kh) * 8192 + 2 * 512);              \
  bfr[3] = *(const bf16x8*)((base) + (kh) * 8192 + 3 * 512);

#define LOADA(base, kh, mh)                                               \
  afr[0] = *(const bf16x8*)((base) + (kh) * 8192 + (mh) * 2048 + 0 * 512);\
  afr[1] = *(const bf16x8*)((base) + (kh) * 8192 + (mh) * 2048 + 1 * 512);\
  afr[2] = *(const bf16x8*)((base) + (kh) * 8192 + (mh) * 2048 + 2 * 512);\
  afr[3] = *(const bf16x8*)((base) + (kh) * 8192 + (mh) * 2048 + 3 * 512);

#define PH(mh)                                                            \
  __builtin_amdgcn_s_barrier();                                           \
  asm volatile("s_waitcnt lgkmcnt(0)" ::: "memory");                      \
  __builtin_amdgcn_s_setprio(1);                                          \
  _Pragma("unroll") for (int mm = 0; mm < 4; ++mm)                        \
    _Pragma("unroll") for (int n_ = 0; n_ < 4; ++n_)                      \
      acc[(mh) * 4 + mm][n_] = mfma16(afr[mm], bfr[n_], acc[(mh) * 4 + mm][n_]); \
  __builtin_amdgcn_s_setprio(0);                                          \
  __builtin_amdgcn_s_barrier();

#define VMC(n) asm volatile("s_waitcnt vmcnt(" #n ")" ::: "memory");

template <typename OutT>
__global__ __launch_bounds__(512, 2) void k_gemm8(const u16* __restrict__ A,
                                                  const u16* __restrict__ Bt,
                                                  OutT* __restrict__ C,
                                                  int M, int N, int K) {
  extern __shared__ u16 lds[];
  const int tid = threadIdx.x;
  const int lane = tid & 63, wid = tid >> 6;
  const int l16 = lane & 15, lhi = lane >> 4;
  const int wm = wid >> 2, wn = wid & 3;

  const int nbn = N >> 8;
  int bid = blockIdx.x;
  const int cpx = gridDim.x >> 3;
  bid = (bid & 7) * cpx + (bid >> 3);  // XCD swizzle (grid % 8 == 0)
  const int bm = (bid / nbn) << 8;
  const int bn = (bid % nbn) << 8;

  const u16* Ag = A + (size_t)bm * K;
  const u16* Bg = Bt + (size_t)bn * K;

  // ---- per-thread constant addresses ----
  const int swz = (lhi ^ ((l16 >> 1) & 3)) << 3;     // lane-constant swizzle
  const u16* pA0 = lds + wm * 4096 + l16 * 32 + swz;          // A reads, buf0
  const u16* pA1 = pA0 + 32768;                               // A reads, buf1
  const u16* pB0 = lds + 16384 + wn * 2048 + l16 * 32 + swz;  // B reads, buf0
  const u16* pB1 = pB0 + 32768;                               // B reads, buf1

  const int r0 = tid >> 2, g0 = tid & 3;     // stage chunk 0: rows 0..127
  const int r1 = r0 + 128;                   // stage chunk 1: rows 128..255
  const size_t so0 = (size_t)r0 * K + ((g0 ^ ((r0 >> 1) & 3)) << 3);
  const size_t so1 = (size_t)r1 * K + ((g0 ^ ((r1 >> 1) & 3)) << 3);
  const u16* sA0 = Ag + so0;
  const u16* sA1 = Ag + so1;
  const u16* sB0 = Bg + so0;
  const u16* sB1 = Bg + so1;
  u16* dst0 = lds + wid * 512;               // chunk0 LDS dest (wave-uniform base)
  u16* dst1 = lds + 4096 + wid * 512;        // chunk1 LDS dest

  f32x4 acc[8][4] = {};
  bf16x8 bfr[4], afr[4];

  // ---- prologue: tile0 (buf0) fully; tile1 (buf1) B-k0, A-k0, B-k1
  STAGE2(sA0, sA1, 0, 0);            // A t0 kh0
  STAGE2(sA0, sA1, 32, 8192);        // A t0 kh1
  STAGE2(sB0, sB1, 0, 16384);        // B t0 kh0
  STAGE2(sB0, sB1, 32, 24576);       // B t0 kh1
  STAGE2(sB0, sB1, 64, 49152);       // B t1 kh0
  STAGE2(sA0, sA1, 64, 32768);       // A t1 kh0
  STAGE2(sB0, sB1, 96, 57344);       // B t1 kh1
  VMC(6)
  __builtin_amdgcn_s_barrier();

  const int nt = K >> 6;
  // ---- steady state: branch-free, stages unconditional
  for (int t = 0; t < nt - 2; t += 2) {
    const int kA1 = (t + 1) * 64 + 32;
    const int k2 = (t + 2) * 64;
    const int k3 = (t + 3) * 64;
    // P1: tile t (buf0) kh0 mh0; stage A-k1(t+1) -> buf1 A kh1
    LOADB(pB0, 0)
    LOADA(pA0, 0, 0)
    STAGE2(sA0, sA1, kA1, 40960);
    PH(0)
    // P2: kh0 mh1; stage B-k0(t+2) -> buf0
    LOADA(pA0, 0, 1)
    STAGE2(sB0, sB1, k2, 16384);
    PH(1)
    // P3: kh1 mh0; stage A-k0(t+2) -> buf0
    LOADB(pB0, 1)
    LOADA(pA0, 1, 0)
    STAGE2(sA0, sA1, k2, 0);
    PH(0)
    // P4: kh1 mh1; stage B-k1(t+2) -> buf0; counted vmcnt
    LOADA(pA0, 1, 1)
    STAGE2(sB0, sB1, k2 + 32, 24576);
    VMC(6)
    PH(1)
    // P5: tile t+1 (buf1) kh0 mh0; stage A-k1(t+2) -> buf0
    LOADB(pB1, 0)
    LOADA(pA1, 0, 0)
    STAGE2(sA0, sA1, k2 + 32, 8192);
    PH(0)
    // P6: kh0 mh1; stage B-k0(t+3) -> buf1
    LOADA(pA1, 0, 1)
    STAGE2(sB0, sB1, k3, 49152);
    PH(1)
    // P7: kh1 mh0; stage A-k0(t+3) -> buf1
    LOADB(pB1, 1)
    LOADA(pA1, 1, 0)
    STAGE2(sA0, sA1, k3, 32768);
    PH(0)
    // P8: kh1 mh1; stage B-k1(t+3) -> buf1; counted vmcnt
    LOADA(pA1, 1, 1)
    STAGE2(sB0, sB1, k3 + 32, 57344);
    VMC(6)
    PH(1)
  }
  // ---- tail: last 2 tiles (t == nt-2), only P1's A-kh1 stage remains
  {
    const int kA1 = (nt - 1) * 64 + 32;
    LOADB(pB0, 0)
    LOADA(pA0, 0, 0)
    STAGE2(sA0, sA1, kA1, 40960);
    PH(0)
    LOADA(pA0, 0, 1)
    PH(1)
    LOADB(pB0, 1)
    LOADA(pA0, 1, 0)
    PH(0)
    LOADA(pA0, 1, 1)
    VMC(0)
    PH(1)
    LOADB(pB1, 0)
    LOADA(pA1, 0, 0)
    PH(0)
    LOADA(pA1, 0, 1)
    PH(1)
    LOADB(pB1, 1)
    LOADA(pA1, 1, 0)
    PH(0)
    LOADA(pA1, 1, 1)
    PH(1)
  }

  // ---- epilogue: C write
#pragma unroll
  for (int m = 0; m < 8; ++m) {
    int row = bm + wm * 128 + m * 16 + lhi * 4;
#pragma unroll
    for (int n = 0; n < 4; ++n) {
      int col = bn + wn * 64 + n * 16 + l16;
#pragma unroll
      for (int r = 0; r < 4; ++r) {
        float v = acc[m][n][r];
        size_t idx = (size_t)(row + r) * N + col;
        if constexpr (sizeof(OutT) == 2) C[idx] = f2b(v);
        else C[idx] = v;
      }
    }
  }
}

// ---------------- flash attention (unchanged)
__global__ __launch_bounds__(512) void k_attn(const u16* __restrict__ qr,
                                              const u16* __restrict__ kr,
                                              const u16* __restrict__ vrt,
                                              u16* __restrict__ ao) {
  __shared__ u16 Klds[8192];
  __shared__ u16 Vlds[8192];
  __shared__ u16 Plds[9216];
  int bid = blockIdx.x;
  int qb = bid & 7, h = (bid >> 3) & 31, b = bid >> 8;
  int kvh = h & 7;
  int lane = threadIdx.x & 63, w = threadIdx.x >> 6;
  int l16 = lane & 15, lhi = lane >> 4;
  int qmin = qb * 128 + w * 16;

  const u16* qbase = qr + ((size_t)((b * 32 + h) * 1024) + qmin + l16) * 128;
  bf16x8 aq[4];
#pragma unroll
  for (int kc = 0; kc < 4; ++kc) aq[kc] = *(const bf16x8*)(qbase + kc * 32 + lhi * 8);

  const u16* Kg = kr + (size_t)(b * 8 + kvh) * (1024 * 128);
  const u16* Vg = vrt + (size_t)(b * 8 + kvh) * (128 * 1024);

  float m_run[4] = {-1e30f, -1e30f, -1e30f, -1e30f};
  float l_run[4] = {0.f, 0.f, 0.f, 0.f};
  f32x4 o[8] = {};

  int nkb = 2 * qb + 2;
  for (int kb = 0; kb < nkb; ++kb) {
    int kv0 = kb * 64;
#pragma unroll
    for (int i = 0; i < 2; ++i) {
      int c = w * 128 + i * 64 + lane;
      int krow = c >> 4, g = c & 15;
      GLD16(Kg + (size_t)(kv0 + krow) * 128 + ((g ^ (krow & 7)) * 8),
            Klds + (w * 128 + i * 64) * 8);
    }
#pragma unroll
    for (int i = 0; i < 2; ++i) {
      int c = w * 128 + i * 64 + lane;
      int d = c >> 3, g = c & 7;
      GLD16(Vg + (size_t)d * 1024 + kv0 + ((g ^ (d & 7)) * 8),
            Vlds + (w * 128 + i * 64) * 8);
    }
    __syncthreads();

    f32x4 s[4] = {};
#pragma unroll
    for (int kc = 0; kc < 4; ++kc) {
#pragma unroll
      for (int n = 0; n < 4; ++n) {
        int kv = n * 16 + l16;
        int g = kc * 4 + lhi;
        bf16x8 bk = *(const bf16x8*)(Klds + kv * 128 + ((g ^ (kv & 7)) * 8));
        s[n] = mfma16(aq[kc], bk, s[n]);
      }
    }
    if (kv0 + 63 > qmin) {
#pragma unroll
      for (int n = 0; n < 4; ++n)
#pragma unroll
        for (int r = 0; r < 4; ++r) {
          int q = qmin + lhi * 4 + r;
          int kv = kv0 + n * 16 + l16;
          if (kv > q) s[n][r] = -1e30f;
        }
    }
    float pr[4][4];
#pragma unroll
    for (int r = 0; r < 4; ++r) {
      float mx = fmaxf(fmaxf(s[0][r], s[1][r]), fmaxf(s[2][r], s[3][r]));
      mx = fmaxf(mx, __shfl_xor(mx, 1));
      mx = fmaxf(mx, __shfl_xor(mx, 2));
      mx = fmaxf(mx, __shfl_xor(mx, 4));
      mx = fmaxf(mx, __shfl_xor(mx, 8));
      float mn = fmaxf(m_run[r], mx);
      float sf = __expf(m_run[r] - mn);
      m_run[r] = mn;
      float sum = 0.f;
#pragma unroll
      for (int n = 0; n < 4; ++n) {
        float p = __expf(s[n][r] - mn);
        pr[n][r] = p;
        sum += p;
      }
      sum += __shfl_xor(sum, 1);
      sum += __shfl_xor(sum, 2);
      sum += __shfl_xor(sum, 4);
      sum += __shfl_xor(sum, 8);
      l_run[r] = l_run[r] * sf + sum;
#pragma unroll
      for (int nd = 0; nd < 8; ++nd) o[nd][r] *= sf;
    }
    u16* pw = Plds + w * 1152;
#pragma unroll
    for (int n = 0; n < 4; ++n)
#pragma unroll
      for (int r = 0; r < 4; ++r) pw[(lhi * 4 + r) * 72 + n * 16 + l16] = f2b(pr[n][r]);
#pragma unroll
    for (int kc = 0; kc < 2; ++kc) {
      bf16x8 ap = *(const bf16x8*)(pw + l16 * 72 + kc * 32 + lhi * 8);
#pragma unroll
      for (int nd = 0; nd < 8; ++nd) {
        int d = nd * 16 + l16;
        int g = kc * 4 + lhi;
        bf16x8 bv = *(const bf16x8*)(Vlds + d * 64 + ((g ^ (d & 7)) * 8));
        o[nd] = mfma16(ap, bv, o[nd]);
      }
    }
    __syncthreads();
  }
#pragma unroll
  for (int r = 0; r < 4; ++r) {
    float inv = 1.0f / l_run[r];
    int q = qmin + lhi * 4 + r;
    u16* orow = ao + ((size_t)(b * 1024 + q)) * 4096 + h * 128;
#pragma unroll
    for (int nd = 0; nd < 8; ++nd) orow[nd * 16 + l16] = f2b(o[nd][r] * inv);
  }
}

extern "C" void kernel_launch(void* const* d_in, const int* in_sizes, int n_in,
                              void* d_out, int out_size, void* d_ws, size_t ws_size,
                              hipStream_t stream) {
  const float* x = (const float*)d_in[0];
  const float* wq = (const float*)d_in[2];
  const float* wk = (const float*)d_in[3];
  const float* wv = (const float*)d_in[4];
  const float* wo = (const float*)d_in[5];

  char* ws = (char*)d_ws;
  u16* xb = (u16*)(ws + 0);
  u16* wcat = (u16*)(ws + 33554432);
  u16* qr = (u16*)(ws + 0);
  u16* kr = (u16*)(ws + 33554432);
  u16* vrt = (u16*)(ws + 41943040);
  u16* ao = (u16*)(ws + 50331648);
  u16* wob = (u16*)(ws + 83886080);
  float2* tab = (float2*)(ws + 117440512);
  u16* qkv = (u16*)d_out;

  hipFuncSetAttribute((const void*)k_gemm8<u16>,
                      hipFuncAttributeMaxDynamicSharedMemorySize, 131072);
  hipFuncSetAttribute((const void*)k_gemm8<float>,
                      hipFuncAttributeMaxDynamicSharedMemorySize, 131072);

  k_rope_table<<<256, 256, 0, stream>>>(tab);
  k_cast8<<<8192, 256, 0, stream>>>(x, xb);
  k_tcast<<<4096, 256, 0, stream>>>(wq, wcat, 4096, 4096);
  k_tcast<<<1024, 256, 0, stream>>>(wk, wcat + (size_t)4096 * 4096, 4096, 1024);
  k_tcast<<<1024, 256, 0, stream>>>(wv, wcat + (size_t)5120 * 4096, 4096, 1024);
  k_tcast<<<4096, 256, 0, stream>>>(wo, wob, 4096, 4096);
  k_gemm8<u16><<<384, 512, 131072, stream>>>(xb, wcat, qkv, 4096, 6144, 4096);
  k_rope<<<40960, 256, 0, stream>>>(qkv, tab, qr, kr);
  k_vtrans<<<1024, 256, 0, stream>>>(qkv, vrt);
  k_attn<<<1024, 512, 0, stream>>>(qr, kr, vrt, ao);
  k_gemm8<float><<<256, 512, 131072, stream>>>(ao, wob, (float*)d_out, 4096, 4096, 4096);
}